// Round 5
// baseline (429.594 us; speedup 1.0000x reference)
//
#include <hip/hip_runtime.h>
#include <math.h>

// DGPLoss on MI355X — R5: DIAGNOSTIC round (double launch).
// seg_feat: [B=4, C=64, H=512, W=512] f32, dep_true: [4,1,512,512] f32.
// loss = exp(-|dep_c - dep|/10 - sum_c(seg_c_cent - seg_c)^2), masked mean.
//
// R1-R4 are structure-invariant at 363-373 us total; dgp_main never appears in
// the rocprof top-5 (so <158 us) and ~245 us of the window is harness resets.
// To pin dgp_main's intrinsic cost, launch it TWICE: sum and count both double
// so the mean is unchanged, and the marginal dur_us delta (plus the second
// dispatch showing up in the profile) measures the clean-state kernel time T.
//   T ~= 50 us  -> kernel at HBM roofline, revert to single launch + done.
//   T ~= 110 us -> intrinsic BW problem, attack access pattern next.

#define EPSF 1e-8f
#define PH 5
#define HPATCH 102
#define HH 512
#define WW 512
#define CC 64
#define HW (HH * WW)

typedef float vf2 __attribute__((ext_vector_type(2)));

__global__ __launch_bounds__(320) void dgp_main(const float* __restrict__ seg,
                                                const float* __restrict__ dep,
                                                float* __restrict__ ws) {
  const int bid = blockIdx.x;
  const int q   = bid & 3;                  // col quarter (128 cols)
  const int hp  = (bid >> 2) % HPATCH;      // patch row
  const int b   = (bid >> 2) / HPATCH;      // batch
  const int h0  = hp * PH;
  const int hc  = h0 + 2;
  const int qbase = q * 128;

  // patches overlapping this quarter
  const int wp0   = qbase / PH;
  const int wpend = min((qbase + 127) / PH, HPATCH - 1);
  const int nwp   = wpend - wp0 + 1;        // 26 or 27

  __shared__ float s_cent[27 * 65];         // [wpl][c], stride 65 -> bank=(wpl+c)%32
  __shared__ float s_depc[27];
  __shared__ float s_red[10];

  const int tid = threadIdx.x;
  const long seg_b = (long)b * CC * HW;

  // ---- stage per-patch channel centers into LDS (div-free: 10 groups of 32) ----
  {
    const int grp = tid >> 5;               // 0..9 -> channel group
    const int wpl = tid & 31;               // 0..31 -> patch-local
    if (wpl < nwp) {
      const long base = seg_b + (long)hc * WW + (wp0 + wpl) * PH + 2;
      for (int c = grp; c < CC; c += 10) {
        s_cent[wpl * 65 + c] = __builtin_nontemporal_load(seg + base + (long)c * HW);
      }
    }
    if (tid < nwp) {
      s_depc[tid] = dep[((long)b * HH + hc) * WW + (wp0 + tid) * PH + 2];
    }
  }
  __syncthreads();

  const int row  = tid >> 6;                // 0..4 within patch
  const int lane = tid & 63;
  const int col0 = qbase + lane * 2;        // this thread's 2 cols

  int w0 = min(col0 / PH - wp0, nwp - 1);         // clamped; col>=510 masked later
  int w1 = min((col0 + 1) / PH - wp0, nwp - 1);

  const float* cb0 = s_cent + w0 * 65;
  const float* cb1 = s_cent + w1 * 65;

  float acc0 = 0.f, acc1 = 0.f;
  const float* p = seg + seg_b + (long)(h0 + row) * WW + col0;

#pragma unroll 8
  for (int c = 0; c < CC; ++c) {
    vf2 v = __builtin_nontemporal_load((const vf2*)(p + (long)c * HW));
    float d0 = cb0[c] - v.x;
    float d1 = cb1[c] - v.y;
    acc0 = fmaf(d0, d0, acc0);
    acc1 = fmaf(d1, d1, acc1);
  }

  // ---- depth branch + mask + loss for this thread's 2 pixels ----
  vf2 dv = __builtin_nontemporal_load((const vf2*)(dep + ((long)b * HH + h0 + row) * WW + col0));
  float dvals[2] = {dv.x, dv.y};
  float accs[2]  = {acc0, acc1};
  int wls[2]     = {w0, w1};

  float lsum = 0.f, lcnt = 0.f;
#pragma unroll
  for (int j = 0; j < 2; ++j) {
    int col = col0 + j;
    if (col < 510) {
      float dval = dvals[j];
      float dd   = fabsf(s_depc[wls[j]] - dval);
      float ssq  = accs[j];
      bool is_center = (row == 2) && (col % PH == 2);
      bool m = (dd > EPSF) && (ssq > EPSF * EPSF) && (dval > EPSF) && !is_center;
      if (m) {
        lsum += __expf(-(dd * 0.1f + ssq));
        lcnt += 1.f;
      }
    }
  }

  // ---- reduce: wave64 shuffle, then across the 5 waves via LDS ----
#pragma unroll
  for (int off = 32; off > 0; off >>= 1) {
    lsum += __shfl_down(lsum, off, 64);
    lcnt += __shfl_down(lcnt, off, 64);
  }
  if (lane == 0) {
    s_red[row]     = lsum;
    s_red[5 + row] = lcnt;
  }
  __syncthreads();
  if (tid == 0) {
    float a = 0.f, n = 0.f;
#pragma unroll
    for (int w = 0; w < 5; ++w) {
      a += s_red[w];
      n += s_red[5 + w];
    }
    atomicAdd(&ws[0], a);
    atomicAdd(&ws[1], n);
  }
}

__global__ void dgp_final(const float* __restrict__ ws, float* __restrict__ out) {
  out[0] = ws[0] / fmaxf(ws[1], 1.0f);
}

extern "C" void kernel_launch(void* const* d_in, const int* in_sizes, int n_in,
                              void* d_out, int out_size, void* d_ws, size_t ws_size,
                              hipStream_t stream) {
  const float* seg = (const float*)d_in[0];
  const float* dep = (const float*)d_in[1];
  float* out = (float*)d_out;
  float* ws  = (float*)d_ws;

  hipMemsetAsync(d_ws, 0, 2 * sizeof(float), stream);

  const int nblocks = 4 * HPATCH * 4;  // 1632
  // DIAGNOSTIC: two identical launches. Sum and count both double -> mean
  // unchanged. Marginal dur_us delta = clean-state intrinsic kernel time.
  dgp_main<<<dim3(nblocks), dim3(320), 0, stream>>>(seg, dep, ws);
  dgp_main<<<dim3(nblocks), dim3(320), 0, stream>>>(seg, dep, ws);
  dgp_final<<<1, 1, 0, stream>>>(ws, out);
}

// Round 6
// 420.935 us; speedup vs baseline: 1.0206x; 1.0206x over previous
//
#include <hip/hip_runtime.h>
#include <math.h>

// DGPLoss on MI355X — R6: single launch + fused finalize (last-block-done).
// seg_feat: [B=4, C=64, H=512, W=512] f32, dep_true: [4,1,512,512] f32.
// loss = exp(-|dep_c - dep|/10 - sum_c(seg_c_cent - seg_c)^2), masked mean.
//
// Evidence: R5 double-launch diagnostic pinned clean-state kernel T ~= 67 us;
// in-window cost ~110 us overlapping the harness poison drain. Window
// aggregate HBM traffic ~1.9 GB -> ~315 us floor; observed 363. All four
// structural variants (R1-R4) identical in total -> structure exhausted.
// This round: drop the separate dgp_final dispatch (fuse via ticket),
// single dgp_main launch. ws layout: [0]=sum, [1]=count, [2]=ticket.

#define EPSF 1e-8f
#define PH 5
#define HPATCH 102
#define HH 512
#define WW 512
#define CC 64
#define HW (HH * WW)
#define NBLOCKS (4 * HPATCH * 4)  // 1632

typedef float vf2 __attribute__((ext_vector_type(2)));

__global__ __launch_bounds__(320) void dgp_main(const float* __restrict__ seg,
                                                const float* __restrict__ dep,
                                                float* __restrict__ ws,
                                                float* __restrict__ out) {
  const int bid = blockIdx.x;
  const int q   = bid & 3;                  // col quarter (128 cols)
  const int hp  = (bid >> 2) % HPATCH;      // patch row
  const int b   = (bid >> 2) / HPATCH;      // batch
  const int h0  = hp * PH;
  const int hc  = h0 + 2;
  const int qbase = q * 128;

  // patches overlapping this quarter
  const int wp0   = qbase / PH;
  const int wpend = min((qbase + 127) / PH, HPATCH - 1);
  const int nwp   = wpend - wp0 + 1;        // 26 or 27

  __shared__ float s_cent[27 * 65];         // [wpl][c], stride 65 -> bank=(wpl+c)%32
  __shared__ float s_depc[27];
  __shared__ float s_red[10];

  const int tid = threadIdx.x;
  const long seg_b = (long)b * CC * HW;

  // ---- stage per-patch channel centers into LDS (div-free: 10 groups of 32).
  // Normal (allocating) loads: center row hc is re-read by the main stream,
  // so let it sit in L2.
  {
    const int grp = tid >> 5;               // 0..9 -> channel group
    const int wpl = tid & 31;               // 0..31 -> patch-local
    if (wpl < nwp) {
      const long base = seg_b + (long)hc * WW + (wp0 + wpl) * PH + 2;
      for (int c = grp; c < CC; c += 10) {
        s_cent[wpl * 65 + c] = seg[base + (long)c * HW];
      }
    }
    if (tid < nwp) {
      s_depc[tid] = dep[((long)b * HH + hc) * WW + (wp0 + tid) * PH + 2];
    }
  }
  __syncthreads();

  const int row  = tid >> 6;                // 0..4 within patch
  const int lane = tid & 63;
  const int col0 = qbase + lane * 2;        // this thread's 2 cols

  int w0 = min(col0 / PH - wp0, nwp - 1);         // clamped; col>=510 masked later
  int w1 = min((col0 + 1) / PH - wp0, nwp - 1);

  const float* cb0 = s_cent + w0 * 65;
  const float* cb1 = s_cent + w1 * 65;

  float acc0 = 0.f, acc1 = 0.f;
  const float* p = seg + seg_b + (long)(h0 + row) * WW + col0;

#pragma unroll 8
  for (int c = 0; c < CC; ++c) {
    vf2 v = __builtin_nontemporal_load((const vf2*)(p + (long)c * HW));
    float d0 = cb0[c] - v.x;
    float d1 = cb1[c] - v.y;
    acc0 = fmaf(d0, d0, acc0);
    acc1 = fmaf(d1, d1, acc1);
  }

  // ---- depth branch + mask + loss for this thread's 2 pixels ----
  vf2 dv = __builtin_nontemporal_load((const vf2*)(dep + ((long)b * HH + h0 + row) * WW + col0));
  float dvals[2] = {dv.x, dv.y};
  float accs[2]  = {acc0, acc1};
  int wls[2]     = {w0, w1};

  float lsum = 0.f, lcnt = 0.f;
#pragma unroll
  for (int j = 0; j < 2; ++j) {
    int col = col0 + j;
    if (col < 510) {
      float dval = dvals[j];
      float dd   = fabsf(s_depc[wls[j]] - dval);
      float ssq  = accs[j];
      bool is_center = (row == 2) && (col % PH == 2);
      bool m = (dd > EPSF) && (ssq > EPSF * EPSF) && (dval > EPSF) && !is_center;
      if (m) {
        lsum += __expf(-(dd * 0.1f + ssq));
        lcnt += 1.f;
      }
    }
  }

  // ---- reduce: wave64 shuffle, then across the 5 waves via LDS ----
#pragma unroll
  for (int off = 32; off > 0; off >>= 1) {
    lsum += __shfl_down(lsum, off, 64);
    lcnt += __shfl_down(lcnt, off, 64);
  }
  if (lane == 0) {
    s_red[row]     = lsum;
    s_red[5 + row] = lcnt;
  }
  __syncthreads();

  // ---- global accumulate + fused finalize (last block done) ----
  if (tid == 0) {
    float a = 0.f, n = 0.f;
#pragma unroll
    for (int w = 0; w < 5; ++w) {
      a += s_red[w];
      n += s_red[5 + w];
    }
    atomicAdd(&ws[0], a);
    atomicAdd(&ws[1], n);
    __threadfence();  // make my adds visible before taking a ticket
    unsigned t = atomicAdd((unsigned*)(ws + 2), 1u);
    if (t == NBLOCKS - 1) {
      // Every other block's adds precede its ticket increment (fenced);
      // atomic RMW reads below observe all prior atomics at the same address.
      float S = atomicAdd(&ws[0], 0.0f);
      float N = atomicAdd(&ws[1], 0.0f);
      out[0] = S / fmaxf(N, 1.0f);
    }
  }
}

extern "C" void kernel_launch(void* const* d_in, const int* in_sizes, int n_in,
                              void* d_out, int out_size, void* d_ws, size_t ws_size,
                              hipStream_t stream) {
  const float* seg = (const float*)d_in[0];
  const float* dep = (const float*)d_in[1];
  float* out = (float*)d_out;
  float* ws  = (float*)d_ws;

  hipMemsetAsync(d_ws, 0, 3 * sizeof(float), stream);  // sum, count, ticket

  dgp_main<<<dim3(NBLOCKS), dim3(320), 0, stream>>>(seg, dep, ws, out);
}